// Round 1
// baseline (123.756 us; speedup 1.0000x reference)
//
#include <hip/hip_runtime.h>

#define B_ 4
#define L_ 4096
#define D_ 64
#define N_ 16
#define CHUNK 32
#define NCHUNK (L_ / CHUNK)   // 128

constexpr float DT_  = 0.1f;
constexpr float EPS_ = 1e-6f;

// ---------------------------------------------------------------------------
// K1: per-(b,l) projections. One wave (64 threads) per position.
// Computes delta = softplus(x.Wd + bd) + DT, then per n:
//   a[n] = exp(A[n]*delta)
//   g[n] = (a-1)*delta*Bm[n] / (A[n]*delta + EPS)
//   Cm[n]
// Stores P[bl*32 + n] = a, P[bl*32 + 16 + n] = g, Cm[bl*16+n].
// ---------------------------------------------------------------------------
__global__ __launch_bounds__(64) void proj_kernel(
    const float* __restrict__ x,  const float* __restrict__ A,
    const float* __restrict__ Wb, const float* __restrict__ bb,
    const float* __restrict__ Wc, const float* __restrict__ bc,
    const float* __restrict__ Wd, const float* __restrict__ bd,
    float* __restrict__ P, float* __restrict__ Cm)
{
    const int bl   = blockIdx.x;       // b*L + l
    const int lane = threadIdx.x;      // 0..63 == d

    float xd = x[(size_t)bl * D_ + lane];
    __shared__ float xs[D_];
    xs[lane] = xd;

    // delta: wave-wide dot(x, Wd)
    float p = xd * Wd[lane];
    #pragma unroll
    for (int m = 32; m >= 1; m >>= 1) p += __shfl_xor(p, m, 64);
    float z = p + bd[0];
    // stable softplus: max(z,0) + log1p(exp(-|z|))
    float delta = fmaxf(z, 0.0f) + log1pf(expf(-fabsf(z))) + DT_;

    __syncthreads();

    if (lane < 32) {
        const int n = lane & 15;
        const float* W  = (lane < 16) ? Wb : Wc;
        float acc = (lane < 16) ? bb[n] : bc[n];
        #pragma unroll
        for (int d = 0; d < D_; d++) acc += xs[d] * W[n * D_ + d];

        if (lane < 16) {
            float An  = A[n];              // row 0 of (D,N) A; rows identical (S4D-Real)
            float tmp = An * delta;
            float a   = expf(tmp);
            float g   = (a - 1.0f) * delta * acc / (tmp + EPS_);
            P[(size_t)bl * 32 + n]      = a;
            P[(size_t)bl * 32 + 16 + n] = g;
        } else {
            Cm[(size_t)bl * 16 + n] = acc;
        }
    }
}

// ---------------------------------------------------------------------------
// K2a: per-chunk local scan (zero initial state). One wave per (b, chunk).
// Lane = d; h[16] in registers. Also tracks cumulative decay per n.
// ---------------------------------------------------------------------------
__global__ __launch_bounds__(64) void scan_local(
    const float* __restrict__ x, const float* __restrict__ P,
    float* __restrict__ S, float* __restrict__ Cdec)
{
    const int b = blockIdx.x / NCHUNK;
    const int c = blockIdx.x % NCHUNK;
    const int d = threadIdx.x;

    float h[N_], cum[N_];
    #pragma unroll
    for (int n = 0; n < N_; n++) { h[n] = 0.0f; cum[n] = 1.0f; }

    const int l0 = c * CHUNK;
    for (int l = l0; l < l0 + CHUNK; l++) {
        const int base = b * L_ + l;
        float xd = x[(size_t)base * D_ + d];
        const float* pp = P + (size_t)base * 32;
        #pragma unroll
        for (int n = 0; n < N_; n++) {
            float a = pp[n];
            float g = pp[16 + n];
            h[n]   = a * h[n] + g * xd;
            cum[n] *= a;
        }
    }

    const int sbase = (b * NCHUNK + c) * N_;
    #pragma unroll
    for (int n = 0; n < N_; n++)
        S[(size_t)(sbase + n) * D_ + d] = h[n];
    if (d == 0) {
        #pragma unroll
        for (int n = 0; n < N_; n++) Cdec[sbase + n] = cum[n];
    }
}

// ---------------------------------------------------------------------------
// K2b: cross-chunk exclusive scan. One thread per (b,n,d) = 4096 threads.
// Converts S (chunk-final local states) in-place into chunk-initial states.
// ---------------------------------------------------------------------------
__global__ __launch_bounds__(256) void combine(
    float* __restrict__ S, const float* __restrict__ Cdec)
{
    const int g = blockIdx.x * 256 + threadIdx.x;   // 0 .. B*N*D-1
    const int b = g / (N_ * D_);
    const int r = g % (N_ * D_);
    const int n = r / D_;
    const int d = r % D_;

    float run = 0.0f;
    for (int c = 0; c < NCHUNK; c++) {
        const size_t idx = (size_t)((b * NCHUNK + c) * N_ + n) * D_ + d;
        float s = S[idx];
        S[idx] = run;                                // exclusive prefix
        run = Cdec[(b * NCHUNK + c) * N_ + n] * run + s;
    }
}

// ---------------------------------------------------------------------------
// K2c: replay chunk scan with true initial state; produce output.
// out[b,l,d] = sum_n Cm[b,l,n] * h[b,l,d,n]
// ---------------------------------------------------------------------------
__global__ __launch_bounds__(64) void scan_out(
    const float* __restrict__ x, const float* __restrict__ P,
    const float* __restrict__ Cmat, const float* __restrict__ S,
    float* __restrict__ out)
{
    const int b = blockIdx.x / NCHUNK;
    const int c = blockIdx.x % NCHUNK;
    const int d = threadIdx.x;

    float h[N_];
    const int sbase = (b * NCHUNK + c) * N_;
    #pragma unroll
    for (int n = 0; n < N_; n++)
        h[n] = S[(size_t)(sbase + n) * D_ + d];

    const int l0 = c * CHUNK;
    for (int l = l0; l < l0 + CHUNK; l++) {
        const int base = b * L_ + l;
        float xd = x[(size_t)base * D_ + d];
        const float* pp = P + (size_t)base * 32;
        const float* cc = Cmat + (size_t)base * 16;
        float acc = 0.0f;
        #pragma unroll
        for (int n = 0; n < N_; n++) {
            float a = pp[n];
            float g = pp[16 + n];
            h[n] = a * h[n] + g * xd;
            acc += cc[n] * h[n];
        }
        out[(size_t)base * D_ + d] = acc;
    }
}

// ---------------------------------------------------------------------------
extern "C" void kernel_launch(void* const* d_in, const int* in_sizes, int n_in,
                              void* d_out, int out_size, void* d_ws, size_t ws_size,
                              hipStream_t stream)
{
    const float* x  = (const float*)d_in[0];
    const float* A  = (const float*)d_in[1];
    const float* Wb = (const float*)d_in[2];
    const float* bb = (const float*)d_in[3];
    const float* Wc = (const float*)d_in[4];
    const float* bc = (const float*)d_in[5];
    const float* Wd = (const float*)d_in[6];
    const float* bd = (const float*)d_in[7];
    float* out = (float*)d_out;

    // workspace carve (floats):
    //   P    : B*L*32            = 524288
    //   Cm   : B*L*16            = 262144
    //   S    : B*NCHUNK*N*D      = 524288
    //   Cdec : B*NCHUNK*N        = 8192
    // total ~5.3 MB
    float* P    = (float*)d_ws;
    float* Cm   = P  + (size_t)B_ * L_ * 32;
    float* S    = Cm + (size_t)B_ * L_ * 16;
    float* Cdec = S  + (size_t)B_ * NCHUNK * N_ * D_;

    proj_kernel<<<B_ * L_, 64, 0, stream>>>(x, A, Wb, bb, Wc, bc, Wd, bd, P, Cm);
    scan_local<<<B_ * NCHUNK, 64, 0, stream>>>(x, P, S, Cdec);
    combine<<<(B_ * N_ * D_) / 256, 256, 0, stream>>>(S, Cdec);
    scan_out<<<B_ * NCHUNK, 64, 0, stream>>>(x, P, Cm, S, out);
}

// Round 2
// 115.929 us; speedup vs baseline: 1.0675x; 1.0675x over previous
//
#include <hip/hip_runtime.h>

#define B_ 4
#define L_ 4096
#define D_ 64
#define N_ 16
#define CHUNK 32
#define NCHUNK (L_ / CHUNK)        // 128
#define TOTCHUNK (B_ * NCHUNK)     // 512
#define POS (B_ * L_)              // 16384
#define POS_PER_BLK 8

constexpr float DT_  = 0.1f;
constexpr float EPS_ = 1e-6f;

// ---------------------------------------------------------------------------
// K1: projections. 2048 blocks x 64 threads (1 wave); block handles 8
// consecutive positions. W rows live in registers (loaded once per block);
// each output's K=64 dot is split across two lanes (halves) + shfl combine,
// so all 64 lanes are busy.
// Outputs: P[p*32 + n] = a[n], P[p*32+16+n] = g[n], Cm[p*16+n].
// ---------------------------------------------------------------------------
__global__ __launch_bounds__(64) void proj_kernel(
    const float* __restrict__ x,  const float* __restrict__ A,
    const float* __restrict__ Wb, const float* __restrict__ bb,
    const float* __restrict__ Wc, const float* __restrict__ bc,
    const float* __restrict__ Wd, const float* __restrict__ bd,
    float* __restrict__ P, float* __restrict__ Cm)
{
    const int lane = threadIdx.x;
    const int o    = lane & 31;      // output row: 0-15 -> Bm[n], 16-31 -> Cm[n]
    const int h2   = lane >> 5;      // which half of K this lane covers
    __shared__ float xs[D_];

    // W rows in registers: wreg[k] = Wrow[o][h2*32 + k]
    float wreg[32];
    const float* Wrow = (o < 16) ? (Wb + o * D_) : (Wc + (o - 16) * D_);
    const float4* w4p = (const float4*)(Wrow + h2 * 32);
    #pragma unroll
    for (int j = 0; j < 8; j++) {
        float4 w4 = w4p[j];
        wreg[4*j+0] = w4.x; wreg[4*j+1] = w4.y;
        wreg[4*j+2] = w4.z; wreg[4*j+3] = w4.w;
    }
    const float wd   = Wd[lane];
    const float bd0  = bd[0];
    const float An   = A[lane & 15];                 // row 0 of (D,N); rows identical
    const float bias = (o < 16) ? bb[o] : bc[o - 16];

    const int p0 = blockIdx.x * POS_PER_BLK;
    for (int p = p0; p < p0 + POS_PER_BLK; p++) {
        float xd = x[(size_t)p * D_ + lane];

        // delta = softplus(x . Wd + bd) + DT  (full-wave butterfly reduce)
        float r = xd * wd;
        #pragma unroll
        for (int m = 32; m >= 1; m >>= 1) r += __shfl_xor(r, m, 64);
        float z = r + bd0;
        float delta = fmaxf(z, 0.0f) + log1pf(expf(-fabsf(z))) + DT_;

        __syncthreads();            // guard vs previous iteration's xs reads
        xs[lane] = xd;
        __syncthreads();

        // half-K partial dot from LDS (broadcast reads), W from registers
        float acc = 0.0f;
        const float4* xs4 = (const float4*)(xs + h2 * 32);
        #pragma unroll
        for (int j = 0; j < 8; j++) {
            float4 v = xs4[j];
            acc += v.x * wreg[4*j+0] + v.y * wreg[4*j+1]
                 + v.z * wreg[4*j+2] + v.w * wreg[4*j+3];
        }
        acc += __shfl_xor(acc, 32, 64);   // combine halves; lanes 0-31 hold full dots

        if (lane < 16) {
            float Bm  = acc + bias;
            float tmp = An * delta;
            float a   = expf(tmp);
            float g   = (a - 1.0f) * delta * Bm / (tmp + EPS_);
            P[(size_t)p * 32 + lane]      = a;
            P[(size_t)p * 32 + 16 + lane] = g;
        } else if (lane < 32) {
            Cm[(size_t)p * 16 + (lane - 16)] = acc + bias;
        }
    }
}

// ---------------------------------------------------------------------------
// K2: per-chunk local scan, zero init. 512 blocks x 64 threads (1 wave).
// Chunk's x/P staged to LDS with coalesced float4 loads; inner loop is
// LDS-only (broadcast b128 reads for a/g).
// ---------------------------------------------------------------------------
__global__ __launch_bounds__(64) void scan_local(
    const float* __restrict__ x, const float* __restrict__ P,
    float* __restrict__ S, float* __restrict__ Cdec)
{
    const int gc    = blockIdx.x;            // global chunk 0..511
    const int batch = gc / NCHUNK;
    const int c     = gc % NCHUNK;
    const int lane  = threadIdx.x;
    const int base0 = batch * L_ + c * CHUNK;

    __shared__ float xs[CHUNK * D_];         // 8 KB
    __shared__ float ag[CHUNK * 32];         // 4 KB

    const float4* xg  = (const float4*)(x + (size_t)base0 * D_);
    float4*       xsv = (float4*)xs;
    #pragma unroll
    for (int i = 0; i < 8; i++) xsv[i * 64 + lane] = xg[i * 64 + lane];
    const float4* pg  = (const float4*)(P + (size_t)base0 * 32);
    float4*       agv = (float4*)ag;
    #pragma unroll
    for (int i = 0; i < 4; i++) agv[i * 64 + lane] = pg[i * 64 + lane];
    __syncthreads();

    float h[N_], cum[N_];
    #pragma unroll
    for (int n = 0; n < N_; n++) { h[n] = 0.0f; cum[n] = 1.0f; }

    for (int s = 0; s < CHUNK; s++) {
        float xd = xs[s * D_ + lane];
        const float4* row = (const float4*)(ag + s * 32);
        #pragma unroll
        for (int q = 0; q < 4; q++) {
            float4 a4 = row[q];
            float4 g4 = row[4 + q];
            h[4*q+0] = a4.x * h[4*q+0] + g4.x * xd;  cum[4*q+0] *= a4.x;
            h[4*q+1] = a4.y * h[4*q+1] + g4.y * xd;  cum[4*q+1] *= a4.y;
            h[4*q+2] = a4.z * h[4*q+2] + g4.z * xd;  cum[4*q+2] *= a4.z;
            h[4*q+3] = a4.w * h[4*q+3] + g4.w * xd;  cum[4*q+3] *= a4.w;
        }
    }

    #pragma unroll
    for (int n = 0; n < N_; n++)
        S[(size_t)(gc * N_ + n) * D_ + lane] = h[n];
    if (lane == 0) {
        #pragma unroll
        for (int n = 0; n < N_; n++) Cdec[gc * N_ + n] = cum[n];
    }
}

// ---------------------------------------------------------------------------
// K3: cross-chunk exclusive scan. 64 blocks x 64 threads; block = (b,n),
// thread = d. Cdec loads are wave-uniform (scalar path); unroll-4 lets the
// compiler pipeline S loads ahead of the fma chain.
// ---------------------------------------------------------------------------
__global__ __launch_bounds__(64) void combine(
    float* __restrict__ S, const float* __restrict__ Cdec)
{
    const int b = blockIdx.x >> 4;
    const int n = blockIdx.x & 15;
    const int d = threadIdx.x;

    float run = 0.0f;
    #pragma unroll 4
    for (int c = 0; c < NCHUNK; c++) {
        const int    gc  = b * NCHUNK + c;
        const size_t idx = (size_t)(gc * N_ + n) * D_ + d;
        float s = S[idx];
        float a = Cdec[gc * N_ + n];
        S[idx] = run;                        // exclusive prefix
        run = a * run + s;
    }
}

// ---------------------------------------------------------------------------
// K4: replay with true init; produce output. Same LDS staging as K2 + Cm.
// ---------------------------------------------------------------------------
__global__ __launch_bounds__(64) void scan_out(
    const float* __restrict__ x, const float* __restrict__ P,
    const float* __restrict__ Cmat, const float* __restrict__ S,
    float* __restrict__ out)
{
    const int gc    = blockIdx.x;
    const int batch = gc / NCHUNK;
    const int c     = gc % NCHUNK;
    const int lane  = threadIdx.x;
    const int base0 = batch * L_ + c * CHUNK;

    __shared__ float xs[CHUNK * D_];         // 8 KB
    __shared__ float ag[CHUNK * 32];         // 4 KB
    __shared__ float cm[CHUNK * N_];         // 2 KB

    const float4* xg  = (const float4*)(x + (size_t)base0 * D_);
    float4*       xsv = (float4*)xs;
    #pragma unroll
    for (int i = 0; i < 8; i++) xsv[i * 64 + lane] = xg[i * 64 + lane];
    const float4* pg  = (const float4*)(P + (size_t)base0 * 32);
    float4*       agv = (float4*)ag;
    #pragma unroll
    for (int i = 0; i < 4; i++) agv[i * 64 + lane] = pg[i * 64 + lane];
    const float4* cg  = (const float4*)(Cmat + (size_t)base0 * 16);
    float4*       cmv = (float4*)cm;
    #pragma unroll
    for (int i = 0; i < 2; i++) cmv[i * 64 + lane] = cg[i * 64 + lane];
    __syncthreads();

    float h[N_];
    #pragma unroll
    for (int n = 0; n < N_; n++)
        h[n] = S[(size_t)(gc * N_ + n) * D_ + lane];

    for (int s = 0; s < CHUNK; s++) {
        float xd = xs[s * D_ + lane];
        const float4* row = (const float4*)(ag + s * 32);
        const float4* crw = (const float4*)(cm + s * 16);
        float acc = 0.0f;
        #pragma unroll
        for (int q = 0; q < 4; q++) {
            float4 a4 = row[q];
            float4 g4 = row[4 + q];
            float4 c4 = crw[q];
            h[4*q+0] = a4.x * h[4*q+0] + g4.x * xd;  acc += c4.x * h[4*q+0];
            h[4*q+1] = a4.y * h[4*q+1] + g4.y * xd;  acc += c4.y * h[4*q+1];
            h[4*q+2] = a4.z * h[4*q+2] + g4.z * xd;  acc += c4.z * h[4*q+2];
            h[4*q+3] = a4.w * h[4*q+3] + g4.w * xd;  acc += c4.w * h[4*q+3];
        }
        out[(size_t)(base0 + s) * D_ + lane] = acc;
    }
}

// ---------------------------------------------------------------------------
extern "C" void kernel_launch(void* const* d_in, const int* in_sizes, int n_in,
                              void* d_out, int out_size, void* d_ws, size_t ws_size,
                              hipStream_t stream)
{
    const float* x  = (const float*)d_in[0];
    const float* A  = (const float*)d_in[1];
    const float* Wb = (const float*)d_in[2];
    const float* bb = (const float*)d_in[3];
    const float* Wc = (const float*)d_in[4];
    const float* bc = (const float*)d_in[5];
    const float* Wd = (const float*)d_in[6];
    const float* bd = (const float*)d_in[7];
    float* out = (float*)d_out;

    // workspace carve (floats): P 524288 | Cm 262144 | S 524288 | Cdec 8192
    float* P    = (float*)d_ws;
    float* Cm   = P  + (size_t)B_ * L_ * 32;
    float* S    = Cm + (size_t)B_ * L_ * 16;
    float* Cdec = S  + (size_t)TOTCHUNK * N_ * D_;

    proj_kernel<<<POS / POS_PER_BLK, 64, 0, stream>>>(x, A, Wb, bb, Wc, bc, Wd, bd, P, Cm);
    scan_local<<<TOTCHUNK, 64, 0, stream>>>(x, P, S, Cdec);
    combine<<<B_ * N_, 64, 0, stream>>>(S, Cdec);
    scan_out<<<TOTCHUNK, 64, 0, stream>>>(x, P, Cm, S, out);
}

// Round 3
// 109.961 us; speedup vs baseline: 1.1255x; 1.0543x over previous
//
#include <hip/hip_runtime.h>

#define B_ 4
#define L_ 4096
#define D_ 64
#define N_ 16
#define CHUNK 16
#define NCHUNK (L_ / CHUNK)        // 256
#define TOTCHUNK (B_ * NCHUNK)     // 1024
#define POS (B_ * L_)              // 16384
#define POS_PER_BLK 8

constexpr float DT_  = 0.1f;
constexpr float EPS_ = 1e-6f;

// ---------------------------------------------------------------------------
// K1: projections. 2048 blocks x 64 threads; block handles 8 positions.
// All 8 positions' x staged to LDS up front (ONE barrier per block); the 8
// delta butterfly-reductions run interleaved so their shfl chains pipeline.
// W rows in registers; K=64 dot split across lane halves + shfl combine.
// Outputs: P[p*32 + n] = a[n], P[p*32+16+n] = g[n], Cm[p*16+n].
// ---------------------------------------------------------------------------
__global__ __launch_bounds__(64) void proj_kernel(
    const float* __restrict__ x,  const float* __restrict__ A,
    const float* __restrict__ Wb, const float* __restrict__ bb,
    const float* __restrict__ Wc, const float* __restrict__ bc,
    const float* __restrict__ Wd, const float* __restrict__ bd,
    float* __restrict__ P, float* __restrict__ Cm)
{
    const int lane = threadIdx.x;
    const int o    = lane & 31;      // output row: 0-15 -> Bm[n], 16-31 -> Cm[n]
    const int h2   = lane >> 5;      // which K-half this lane covers
    __shared__ float xs[POS_PER_BLK * D_];   // 2 KB

    // W rows in registers
    float wreg[32];
    const float* Wrow = (o < 16) ? (Wb + o * D_) : (Wc + (o - 16) * D_);
    const float4* w4p = (const float4*)(Wrow + h2 * 32);
    #pragma unroll
    for (int j = 0; j < 8; j++) {
        float4 w4 = w4p[j];
        wreg[4*j+0] = w4.x; wreg[4*j+1] = w4.y;
        wreg[4*j+2] = w4.z; wreg[4*j+3] = w4.w;
    }
    const float wd   = Wd[lane];
    const float bd0  = bd[0];
    const float An   = A[lane & 15];                 // row 0; rows identical (S4D-Real)
    const float bias = (o < 16) ? bb[o] : bc[o - 16];

    const int p0 = blockIdx.x * POS_PER_BLK;

    // stage 8 positions of x (512 floats) with two float4 loads per lane
    const float4* xg  = (const float4*)(x + (size_t)p0 * D_);
    float4*       xsv = (float4*)xs;
    xsv[lane]      = xg[lane];
    xsv[64 + lane] = xg[64 + lane];
    __syncthreads();

    // delta for all 8 positions, butterfly chains interleaved
    float r[POS_PER_BLK];
    #pragma unroll
    for (int p = 0; p < POS_PER_BLK; p++) r[p] = xs[p * D_ + lane] * wd;
    #pragma unroll
    for (int m = 32; m >= 1; m >>= 1) {
        #pragma unroll
        for (int p = 0; p < POS_PER_BLK; p++) r[p] += __shfl_xor(r[p], m, 64);
    }
    float delta[POS_PER_BLK];
    #pragma unroll
    for (int p = 0; p < POS_PER_BLK; p++) {
        float z = r[p] + bd0;
        delta[p] = fmaxf(z, 0.0f) + log1pf(expf(-fabsf(z))) + DT_;
    }

    // Bm / Cm dots + pointwise outputs
    #pragma unroll
    for (int p = 0; p < POS_PER_BLK; p++) {
        float acc = 0.0f;
        const float4* xs4 = (const float4*)(xs + p * D_ + h2 * 32);
        #pragma unroll
        for (int j = 0; j < 8; j++) {
            float4 v = xs4[j];
            acc += v.x * wreg[4*j+0] + v.y * wreg[4*j+1]
                 + v.z * wreg[4*j+2] + v.w * wreg[4*j+3];
        }
        acc += __shfl_xor(acc, 32, 64);   // lanes 0-31 hold full dots
        const int pp = p0 + p;
        if (lane < 16) {
            float Bm  = acc + bias;
            float tmp = An * delta[p];
            float a   = expf(tmp);
            float g   = (a - 1.0f) * delta[p] * Bm / (tmp + EPS_);
            P[(size_t)pp * 32 + lane]      = a;
            P[(size_t)pp * 32 + 16 + lane] = g;
        } else if (lane < 32) {
            Cm[(size_t)pp * 16 + (lane - 16)] = acc + bias;
        }
    }
}

// ---------------------------------------------------------------------------
// K2: per-chunk local scan, zero init. 1024 blocks x 64 threads.
// ---------------------------------------------------------------------------
__global__ __launch_bounds__(64) void scan_local(
    const float* __restrict__ x, const float* __restrict__ P,
    float* __restrict__ S, float* __restrict__ Cdec)
{
    const int gc    = blockIdx.x;            // global chunk 0..1023
    const int batch = gc / NCHUNK;
    const int c     = gc % NCHUNK;
    const int lane  = threadIdx.x;
    const int base0 = batch * L_ + c * CHUNK;

    __shared__ float xs[CHUNK * D_];         // 4 KB
    __shared__ float ag[CHUNK * 32];         // 2 KB

    const float4* xg  = (const float4*)(x + (size_t)base0 * D_);
    float4*       xsv = (float4*)xs;
    #pragma unroll
    for (int i = 0; i < 4; i++) xsv[i * 64 + lane] = xg[i * 64 + lane];
    const float4* pg  = (const float4*)(P + (size_t)base0 * 32);
    float4*       agv = (float4*)ag;
    #pragma unroll
    for (int i = 0; i < 2; i++) agv[i * 64 + lane] = pg[i * 64 + lane];
    __syncthreads();

    float h[N_], cum[N_];
    #pragma unroll
    for (int n = 0; n < N_; n++) { h[n] = 0.0f; cum[n] = 1.0f; }

    for (int s = 0; s < CHUNK; s++) {
        float xd = xs[s * D_ + lane];
        const float4* row = (const float4*)(ag + s * 32);
        #pragma unroll
        for (int q = 0; q < 4; q++) {
            float4 a4 = row[q];
            float4 g4 = row[4 + q];
            h[4*q+0] = a4.x * h[4*q+0] + g4.x * xd;  cum[4*q+0] *= a4.x;
            h[4*q+1] = a4.y * h[4*q+1] + g4.y * xd;  cum[4*q+1] *= a4.y;
            h[4*q+2] = a4.z * h[4*q+2] + g4.z * xd;  cum[4*q+2] *= a4.z;
            h[4*q+3] = a4.w * h[4*q+3] + g4.w * xd;  cum[4*q+3] *= a4.w;
        }
    }

    #pragma unroll
    for (int n = 0; n < N_; n++)
        S[(size_t)(gc * N_ + n) * D_ + lane] = h[n];
    if (lane == 0) {
        #pragma unroll
        for (int n = 0; n < N_; n++) Cdec[gc * N_ + n] = cum[n];
    }
}

// ---------------------------------------------------------------------------
// K3: cross-chunk exclusive scan, 64 blocks x 64 threads; block = (b,n),
// thread = d. Distance-4 software prefetch of S and Cdec so the loop body is
// store + fma only (the 256-long fma chain is the only serial dependency).
// ---------------------------------------------------------------------------
__global__ __launch_bounds__(64) void combine(
    float* __restrict__ S, const float* __restrict__ Cdec)
{
    const int b = blockIdx.x >> 4;
    const int n = blockIdx.x & 15;
    const int d = threadIdx.x;
    const int cb = b * NCHUNK;               // global chunk base

    float run = 0.0f;
    float sbuf[4], abuf[4];
    #pragma unroll
    for (int j = 0; j < 4; j++) {
        sbuf[j] = S[(size_t)((cb + j) * N_ + n) * D_ + d];
        abuf[j] = Cdec[(cb + j) * N_ + n];
    }
    for (int c = 0; c < NCHUNK; c += 4) {
        const int cn = (c + 4 < NCHUNK) ? c + 4 : c;   // last group: dummy reload
        float t[4], u[4];
        #pragma unroll
        for (int j = 0; j < 4; j++) {
            t[j] = S[(size_t)((cb + cn + j) * N_ + n) * D_ + d];
            u[j] = Cdec[(cb + cn + j) * N_ + n];
        }
        #pragma unroll
        for (int j = 0; j < 4; j++) {
            S[(size_t)((cb + c + j) * N_ + n) * D_ + d] = run;  // exclusive prefix
            run = abuf[j] * run + sbuf[j];
        }
        #pragma unroll
        for (int j = 0; j < 4; j++) { sbuf[j] = t[j]; abuf[j] = u[j]; }
    }
}

// ---------------------------------------------------------------------------
// K4: replay with true init; produce output. 1024 blocks x 64 threads.
// ---------------------------------------------------------------------------
__global__ __launch_bounds__(64) void scan_out(
    const float* __restrict__ x, const float* __restrict__ P,
    const float* __restrict__ Cmat, const float* __restrict__ S,
    float* __restrict__ out)
{
    const int gc    = blockIdx.x;
    const int batch = gc / NCHUNK;
    const int c     = gc % NCHUNK;
    const int lane  = threadIdx.x;
    const int base0 = batch * L_ + c * CHUNK;

    __shared__ float xs[CHUNK * D_];         // 4 KB
    __shared__ float ag[CHUNK * 32];         // 2 KB
    __shared__ float cm[CHUNK * N_];         // 1 KB

    const float4* xg  = (const float4*)(x + (size_t)base0 * D_);
    float4*       xsv = (float4*)xs;
    #pragma unroll
    for (int i = 0; i < 4; i++) xsv[i * 64 + lane] = xg[i * 64 + lane];
    const float4* pg  = (const float4*)(P + (size_t)base0 * 32);
    float4*       agv = (float4*)ag;
    #pragma unroll
    for (int i = 0; i < 2; i++) agv[i * 64 + lane] = pg[i * 64 + lane];
    const float4* cg  = (const float4*)(Cmat + (size_t)base0 * 16);
    float4*       cmv = (float4*)cm;
    cmv[lane] = cg[lane];
    __syncthreads();

    float h[N_];
    #pragma unroll
    for (int n = 0; n < N_; n++)
        h[n] = S[(size_t)(gc * N_ + n) * D_ + lane];

    for (int s = 0; s < CHUNK; s++) {
        float xd = xs[s * D_ + lane];
        const float4* row = (const float4*)(ag + s * 32);
        const float4* crw = (const float4*)(cm + s * 16);
        float acc = 0.0f;
        #pragma unroll
        for (int q = 0; q < 4; q++) {
            float4 a4 = row[q];
            float4 g4 = row[4 + q];
            float4 c4 = crw[q];
            h[4*q+0] = a4.x * h[4*q+0] + g4.x * xd;  acc += c4.x * h[4*q+0];
            h[4*q+1] = a4.y * h[4*q+1] + g4.y * xd;  acc += c4.y * h[4*q+1];
            h[4*q+2] = a4.z * h[4*q+2] + g4.z * xd;  acc += c4.z * h[4*q+2];
            h[4*q+3] = a4.w * h[4*q+3] + g4.w * xd;  acc += c4.w * h[4*q+3];
        }
        out[(size_t)(base0 + s) * D_ + lane] = acc;
    }
}

// ---------------------------------------------------------------------------
extern "C" void kernel_launch(void* const* d_in, const int* in_sizes, int n_in,
                              void* d_out, int out_size, void* d_ws, size_t ws_size,
                              hipStream_t stream)
{
    const float* x  = (const float*)d_in[0];
    const float* A  = (const float*)d_in[1];
    const float* Wb = (const float*)d_in[2];
    const float* bb = (const float*)d_in[3];
    const float* Wc = (const float*)d_in[4];
    const float* bc = (const float*)d_in[5];
    const float* Wd = (const float*)d_in[6];
    const float* bd = (const float*)d_in[7];
    float* out = (float*)d_out;

    // workspace carve (floats): P 524288 | Cm 262144 | S 1048576 | Cdec 16384
    float* P    = (float*)d_ws;
    float* Cm   = P  + (size_t)B_ * L_ * 32;
    float* S    = Cm + (size_t)B_ * L_ * 16;
    float* Cdec = S  + (size_t)TOTCHUNK * N_ * D_;

    proj_kernel<<<POS / POS_PER_BLK, 64, 0, stream>>>(x, A, Wb, bb, Wc, bc, Wd, bd, P, Cm);
    scan_local<<<TOTCHUNK, 64, 0, stream>>>(x, P, S, Cdec);
    combine<<<B_ * N_, 64, 0, stream>>>(S, Cdec);
    scan_out<<<TOTCHUNK, 64, 0, stream>>>(x, P, Cm, S, out);
}

// Round 5
// 108.003 us; speedup vs baseline: 1.1459x; 1.0181x over previous
//
#include <hip/hip_runtime.h>

#define B_ 4
#define L_ 4096
#define D_ 64
#define N_ 16
#define CHUNK 16
#define NCHUNK (L_ / CHUNK)        // 256
#define TOTCHUNK (B_ * NCHUNK)     // 1024

constexpr float DT_  = 0.1f;
constexpr float EPS_ = 1e-6f;

// ---------------------------------------------------------------------------
// K1: fused projection + local chunk scan. 1024 blocks x 64 threads (1 wave).
// Per block (= one 16-step chunk):
//   stage x -> LDS (coalesced float4);
//   delta via 16 interleaved 64-lane butterfly reductions;
//   Bm/Cm dots with W rows in registers (K=64 split across lane halves);
//   a/g/cm written to LDS (consumed by local scan) AND to global P/Cm (for K3);
//   local scan (zero init) -> chunk-final state S + chunk decay Cdec.
// ---------------------------------------------------------------------------
__global__ __launch_bounds__(64) void proj_scan_kernel(
    const float* __restrict__ x,  const float* __restrict__ A,
    const float* __restrict__ Wb, const float* __restrict__ bb,
    const float* __restrict__ Wc, const float* __restrict__ bc,
    const float* __restrict__ Wd, const float* __restrict__ bd,
    float* __restrict__ P, float* __restrict__ Cm,
    float* __restrict__ S, float* __restrict__ Cdec)
{
    const int gc    = blockIdx.x;              // global chunk 0..1023
    const int batch = gc >> 8;                 // gc / NCHUNK
    const int c     = gc & (NCHUNK - 1);
    const int lane  = threadIdx.x;
    const int base0 = batch * L_ + c * CHUNK;

    __shared__ float xs[CHUNK * D_];           // 4 KB
    __shared__ float ag[CHUNK * 32];           // 2 KB

    // ---- stage chunk's x ----
    const float4* xg  = (const float4*)(x + (size_t)base0 * D_);
    float4*       xsv = (float4*)xs;
    #pragma unroll
    for (int i = 0; i < 4; i++) xsv[i * 64 + lane] = xg[i * 64 + lane];

    // ---- W rows in registers (overlaps x staging latency) ----
    const int o  = lane & 31;                  // 0-15 -> Bm row, 16-31 -> Cm row
    const int h2 = lane >> 5;                  // K-half
    float wreg[32];
    const float* Wrow = (o < 16) ? (Wb + o * D_) : (Wc + (o - 16) * D_);
    const float4* w4p = (const float4*)(Wrow + h2 * 32);
    #pragma unroll
    for (int j = 0; j < 8; j++) {
        float4 w4 = w4p[j];
        wreg[4*j+0] = w4.x; wreg[4*j+1] = w4.y;
        wreg[4*j+2] = w4.z; wreg[4*j+3] = w4.w;
    }
    const float wd   = Wd[lane];
    const float bd0  = bd[0];
    const float An   = A[lane & 15];           // row 0 of (D,N); rows identical
    const float bias = (o < 16) ? bb[o] : bc[o - 16];

    __syncthreads();

    // ---- deltas: 16 butterflies, interleaved so shfl chains pipeline ----
    float r[CHUNK];
    #pragma unroll
    for (int p = 0; p < CHUNK; p++) r[p] = xs[p * D_ + lane] * wd;
    #pragma unroll
    for (int m = 32; m >= 1; m >>= 1) {
        #pragma unroll
        for (int p = 0; p < CHUNK; p++) r[p] += __shfl_xor(r[p], m, 64);
    }
    float delta[CHUNK];
    #pragma unroll
    for (int p = 0; p < CHUNK; p++) {
        float z = r[p] + bd0;
        delta[p] = fmaxf(z, 0.0f) + log1pf(expf(-fabsf(z))) + DT_;
    }

    // ---- Bm/Cm dots -> LDS (for local scan) + global P/Cm (for replay) ----
    #pragma unroll
    for (int p = 0; p < CHUNK; p++) {
        float acc = 0.0f;
        const float4* xs4 = (const float4*)(xs + p * D_ + h2 * 32);
        #pragma unroll
        for (int j = 0; j < 8; j++) {
            float4 v = xs4[j];                 // broadcast LDS reads
            acc += v.x * wreg[4*j+0] + v.y * wreg[4*j+1]
                 + v.z * wreg[4*j+2] + v.w * wreg[4*j+3];
        }
        acc += __shfl_xor(acc, 32, 64);        // lanes 0-31 hold full dots
        const int pp = base0 + p;
        if (lane < 16) {
            float Bm  = acc + bias;
            float tmp = An * delta[p];
            float a   = expf(tmp);
            float g   = (a - 1.0f) * delta[p] * Bm / (tmp + EPS_);
            ag[p * 32 + lane]      = a;
            ag[p * 32 + 16 + lane] = g;
            P[(size_t)pp * 32 + lane]      = a;
            P[(size_t)pp * 32 + 16 + lane] = g;
        } else if (lane < 32) {
            Cm[(size_t)pp * 16 + (lane - 16)] = acc + bias;
        }
    }
    __syncthreads();

    // ---- local scan (zero init), LDS-only inner loop ----
    float h[N_], cum[N_];
    #pragma unroll
    for (int n = 0; n < N_; n++) { h[n] = 0.0f; cum[n] = 1.0f; }
    for (int s = 0; s < CHUNK; s++) {
        float xd = xs[s * D_ + lane];
        const float4* row = (const float4*)(ag + s * 32);
        #pragma unroll
        for (int q = 0; q < 4; q++) {
            float4 a4 = row[q];
            float4 g4 = row[4 + q];
            h[4*q+0] = a4.x * h[4*q+0] + g4.x * xd;  cum[4*q+0] *= a4.x;
            h[4*q+1] = a4.y * h[4*q+1] + g4.y * xd;  cum[4*q+1] *= a4.y;
            h[4*q+2] = a4.z * h[4*q+2] + g4.z * xd;  cum[4*q+2] *= a4.z;
            h[4*q+3] = a4.w * h[4*q+3] + g4.w * xd;  cum[4*q+3] *= a4.w;
        }
    }
    #pragma unroll
    for (int n = 0; n < N_; n++)
        S[(size_t)(gc * N_ + n) * D_ + lane] = h[n];
    if (lane == 0) {
        #pragma unroll
        for (int n = 0; n < N_; n++) Cdec[gc * N_ + n] = cum[n];
    }
}

// ---------------------------------------------------------------------------
// K2: cross-chunk exclusive scan, 64 blocks x 64 threads; block = (b,n),
// thread = d. Distance-4 software prefetch; loop body = store + fma only.
// ---------------------------------------------------------------------------
__global__ __launch_bounds__(64) void combine(
    float* __restrict__ S, const float* __restrict__ Cdec)
{
    const int b = blockIdx.x >> 4;
    const int n = blockIdx.x & 15;
    const int d = threadIdx.x;
    const int cb = b * NCHUNK;

    float run = 0.0f;
    float sbuf[4], abuf[4];
    #pragma unroll
    for (int j = 0; j < 4; j++) {
        sbuf[j] = S[(size_t)((cb + j) * N_ + n) * D_ + d];
        abuf[j] = Cdec[(cb + j) * N_ + n];
    }
    for (int c = 0; c < NCHUNK; c += 4) {
        const int cn = (c + 4 < NCHUNK) ? c + 4 : c;   // last group: dummy reload
        float t[4], u[4];
        #pragma unroll
        for (int j = 0; j < 4; j++) {
            t[j] = S[(size_t)((cb + cn + j) * N_ + n) * D_ + d];
            u[j] = Cdec[(cb + cn + j) * N_ + n];
        }
        #pragma unroll
        for (int j = 0; j < 4; j++) {
            S[(size_t)((cb + c + j) * N_ + n) * D_ + d] = run;  // exclusive prefix
            run = abuf[j] * run + sbuf[j];
        }
        #pragma unroll
        for (int j = 0; j < 4; j++) { sbuf[j] = t[j]; abuf[j] = u[j]; }
    }
}

// ---------------------------------------------------------------------------
// K3: replay with true init; produce output. 1024 blocks x 64 threads.
// ---------------------------------------------------------------------------
__global__ __launch_bounds__(64) void scan_out(
    const float* __restrict__ x, const float* __restrict__ P,
    const float* __restrict__ Cmat, const float* __restrict__ S,
    float* __restrict__ out)
{
    const int gc    = blockIdx.x;
    const int batch = gc >> 8;
    const int c     = gc & (NCHUNK - 1);
    const int lane  = threadIdx.x;
    const int base0 = batch * L_ + c * CHUNK;

    __shared__ float xs[CHUNK * D_];         // 4 KB
    __shared__ float ag[CHUNK * 32];         // 2 KB
    __shared__ float cm[CHUNK * N_];         // 1 KB

    const float4* xg  = (const float4*)(x + (size_t)base0 * D_);
    float4*       xsv = (float4*)xs;
    #pragma unroll
    for (int i = 0; i < 4; i++) xsv[i * 64 + lane] = xg[i * 64 + lane];
    const float4* pg  = (const float4*)(P + (size_t)base0 * 32);
    float4*       agv = (float4*)ag;
    #pragma unroll
    for (int i = 0; i < 2; i++) agv[i * 64 + lane] = pg[i * 64 + lane];
    const float4* cg  = (const float4*)(Cmat + (size_t)base0 * 16);
    float4*       cmv = (float4*)cm;
    cmv[lane] = cg[lane];
    __syncthreads();

    float h[N_];
    #pragma unroll
    for (int n = 0; n < N_; n++)
        h[n] = S[(size_t)(gc * N_ + n) * D_ + lane];

    for (int s = 0; s < CHUNK; s++) {
        float xd = xs[s * D_ + lane];
        const float4* row = (const float4*)(ag + s * 32);
        const float4* crw = (const float4*)(cm + s * 16);
        float acc = 0.0f;
        #pragma unroll
        for (int q = 0; q < 4; q++) {
            float4 a4 = row[q];
            float4 g4 = row[4 + q];
            float4 c4 = crw[q];
            h[4*q+0] = a4.x * h[4*q+0] + g4.x * xd;  acc += c4.x * h[4*q+0];
            h[4*q+1] = a4.y * h[4*q+1] + g4.y * xd;  acc += c4.y * h[4*q+1];
            h[4*q+2] = a4.z * h[4*q+2] + g4.z * xd;  acc += c4.z * h[4*q+2];
            h[4*q+3] = a4.w * h[4*q+3] + g4.w * xd;  acc += c4.w * h[4*q+3];
        }
        out[(size_t)(base0 + s) * D_ + lane] = acc;
    }
}

// ---------------------------------------------------------------------------
extern "C" void kernel_launch(void* const* d_in, const int* in_sizes, int n_in,
                              void* d_out, int out_size, void* d_ws, size_t ws_size,
                              hipStream_t stream)
{
    const float* x  = (const float*)d_in[0];
    const float* A  = (const float*)d_in[1];
    const float* Wb = (const float*)d_in[2];
    const float* bb = (const float*)d_in[3];
    const float* Wc = (const float*)d_in[4];
    const float* bc = (const float*)d_in[5];
    const float* Wd = (const float*)d_in[6];
    const float* bd = (const float*)d_in[7];
    float* out = (float*)d_out;

    // workspace carve (floats): P 524288 | Cm 262144 | S 1048576 | Cdec 16384
    float* P    = (float*)d_ws;
    float* Cm   = P  + (size_t)B_ * L_ * 32;
    float* S    = Cm + (size_t)B_ * L_ * 16;
    float* Cdec = S  + (size_t)TOTCHUNK * N_ * D_;

    proj_scan_kernel<<<TOTCHUNK, 64, 0, stream>>>(x, A, Wb, bb, Wc, bc, Wd, bd,
                                                  P, Cm, S, Cdec);
    combine<<<B_ * N_, 64, 0, stream>>>(S, Cdec);
    scan_out<<<TOTCHUNK, 64, 0, stream>>>(x, P, Cm, S, out);
}